// Round 5
// baseline (250.238 us; speedup 1.0000x reference)
//
#include <hip/hip_runtime.h>

#define HID 128
#define NNODE 10000
#define KN 16
#define ROWS 80000    // BATCH * NNODE
#define NCHUNK 157    // ceil(NNODE/64)

typedef __attribute__((ext_vector_type(8))) short short8;   // 8 bf16 (4 VGPRs)
typedef __attribute__((ext_vector_type(4))) float f32x4;
typedef __attribute__((ext_vector_type(2))) float f32x2;
typedef __attribute__((ext_vector_type(4))) unsigned int u32x4;

__device__ __forceinline__ unsigned short f2b(float f) {
    unsigned u = __float_as_uint(f);
    u += 0x7FFFu + ((u >> 16) & 1u);       // round-to-nearest-even
    return (unsigned short)(u >> 16);
}

// All four weight transposes+converts in one launch.
__global__ __launch_bounds__(256) void wconv_all(
    const float* __restrict__ W1, const float* __restrict__ W2,
    const float* __restrict__ Wu1, const float* __restrict__ Wu2,
    unsigned short* __restrict__ W1t, unsigned short* __restrict__ W2t,
    unsigned short* __restrict__ Wu1t, unsigned short* __restrict__ Wu2t) {
    int idx = blockIdx.x * 256 + threadIdx.x;   // < 90112
    const float* W; unsigned short* Wt; int K; int off;
    if (idx < 8192)       { W = W1;  Wt = W1t;  K = 64;  off = idx; }
    else if (idx < 24576) { W = W2;  Wt = W2t;  K = 128; off = idx - 8192; }
    else if (idx < 57344) { W = Wu1; Wt = Wu1t; K = 256; off = idx - 24576; }
    else                  { W = Wu2; Wt = Wu2t; K = 256; off = idx - 57344; }
    int n = off & 127, k = off >> 7;
    Wt[n * K + k] = f2b(W[off]);
}

// Y[r][j] = relu(A[r][:] @ W[:,j] + bias[j]) via bf16 MFMA.
// Two independent (A,Y) pairs in one launch (grid = 2*1250 when A1 != null).
template<int K, bool AF32>
__global__ __launch_bounds__(256) void embed_mfma(
    const void* __restrict__ A0, const void* __restrict__ A1,
    const unsigned short* __restrict__ Wt, const float* __restrict__ bias,
    unsigned short* __restrict__ Y0, unsigned short* __restrict__ Y1) {
    int g = blockIdx.x;
    const void* Ain = A0; unsigned short* Yb = Y0;
    if (g >= 1250) { Ain = A1; Yb = Y1; g -= 1250; }

    const int wave = threadIdx.x >> 6, lane = threadIdx.x & 63;
    const int lrow = lane & 15, lk = lane >> 4;
    const int m0 = g * 64 + wave * 16;
    const int arow = m0 + lrow;

    short8 a[K / 32];
    if constexpr (AF32) {
        const float* A = (const float*)Ain;
#pragma unroll
        for (int kt = 0; kt < K / 32; ++kt) {
            const float* p = A + (size_t)arow * K + kt * 32 + lk * 8;
            f32x4 f0 = *(const f32x4*)p;
            f32x4 f1 = *(const f32x4*)(p + 4);
            short8 v;
#pragma unroll
            for (int e = 0; e < 4; ++e) { v[e] = (short)f2b(f0[e]); v[4 + e] = (short)f2b(f1[e]); }
            a[kt] = v;
        }
    } else {
        const unsigned short* A = (const unsigned short*)Ain;
#pragma unroll
        for (int kt = 0; kt < K / 32; ++kt)
            a[kt] = *(const short8*)(A + (size_t)arow * K + kt * 32 + lk * 8);
    }

#pragma unroll
    for (int nt = 0; nt < 8; ++nt) {
        f32x4 acc = {0.f, 0.f, 0.f, 0.f};
#pragma unroll
        for (int kt = 0; kt < K / 32; ++kt) {
            short8 b = *(const short8*)(Wt + (nt * 16 + lrow) * K + kt * 32 + lk * 8);
            acc = __builtin_amdgcn_mfma_f32_16x16x32_bf16(a[kt], b, acc, 0, 0, 0);
        }
        const int ocol = nt * 16 + lrow;
        const float bv = bias[ocol];
#pragma unroll
        for (int j = 0; j < 4; ++j) {
            const int orow = m0 + lk * 4 + j;
            float v = acc[j] + bv;
            v = v > 0.f ? v : 0.f;
            Yb[(size_t)orow * HID + ocol] = f2b(v);
        }
    }
}

// Stage A: gather + aggregate, column-split so each XCD's working set is
// 2 x 1.28 MB (L2-resident). grid bid = ((h*NCHUNK + c) << 3) | b.
// 64 rows/block, 8 threads/row (16B each), col-half h. Output: G bf16 [ROWS][128].
__global__ __launch_bounds__(512) void aggr_kernel(
    const unsigned short* __restrict__ SE, const unsigned short* __restrict__ IE,
    const int* __restrict__ sidx, const int* __restrict__ iidx,
    unsigned short* __restrict__ G) {
    __shared__ int sh_idx[64][33];        // padded: conflict-free write & read
    const int t = threadIdx.x;
    const int b = blockIdx.x & 7;
    const int hc = blockIdx.x >> 3;
    const int h = hc >= NCHUNK ? 1 : 0;
    const int c = hc - h * NCHUNK;
    const int n0 = c * 64;

#pragma unroll
    for (int q = 0; q < 4; ++q) {
        const int e = t + q * 512;        // < 2048
        const int r = e >> 5, k = e & 31;
        int nr = n0 + r; if (nr > NNODE - 1) nr = NNODE - 1;
        sh_idx[r][k] = (k < KN) ? sidx[nr * KN + k] : iidx[nr * KN + (k - KN)];
    }
    __syncthreads();

    const int r = t >> 3, p = t & 7;
    const int col0 = h * 64 + p * 8;
    const int n = n0 + r;
    const size_t base = (size_t)b * NNODE * HID + col0;

    f32x2 acc[4];
#pragma unroll
    for (int w = 0; w < 4; ++w) acc[w] = (f32x2){0.f, 0.f};

#pragma unroll
    for (int q = 0; q < 4; ++q) {
        const unsigned short* P = (q < 2) ? SE : IE;   // slots 0-15 sidx, 16-31 iidx
        u32x4 vals[8];
#pragma unroll
        for (int j = 0; j < 8; ++j)
            vals[j] = *(const u32x4*)(P + base + (size_t)sh_idx[r][q * 8 + j] * HID);
#pragma unroll
        for (int j = 0; j < 8; ++j)
#pragma unroll
            for (int w = 0; w < 4; ++w) {
                const unsigned u = vals[j][w];
                acc[w] += (f32x2){__uint_as_float(u << 16), __uint_as_float(u & 0xffff0000u)};
            }
    }

    if (n < NNODE) {
        short8 ov;
#pragma unroll
        for (int w = 0; w < 4; ++w) {
            ov[2 * w]     = (short)f2b(acc[w].x);
            ov[2 * w + 1] = (short)f2b(acc[w].y);
        }
        *(short8*)(G + ((size_t)b * NNODE + n) * HID + col0) = ov;
    }
}

// Stage B: Y = relu([G | H] @ Wut^T + bu), streaming GEMM, no LDS.
// 512 thr / 8 waves; wave w: rows bid*64 + (w&1)*32 + {0,16}, cols (w>>1)*32.
__global__ __launch_bounds__(512) void update_gemm(
    const unsigned short* __restrict__ G, const unsigned short* __restrict__ H,
    const unsigned short* __restrict__ Wut, const float* __restrict__ bu,
    float* __restrict__ Yf, unsigned short* __restrict__ Yb, int writeb) {
    const int t = threadIdx.x, wave = t >> 6, lane = t & 63;
    const int lrow = lane & 15, lk = lane >> 4;
    const int rs = wave & 1, colg = wave >> 1;
    const int m0 = blockIdx.x * 64 + rs * 32;
    const int row0 = m0 + lrow, row1 = m0 + 16 + lrow;

    short8 a0[8], a1[8];
#pragma unroll
    for (int kt = 0; kt < 4; ++kt) {
        a0[kt]     = *(const short8*)(G + (size_t)row0 * HID + kt * 32 + lk * 8);
        a1[kt]     = *(const short8*)(G + (size_t)row1 * HID + kt * 32 + lk * 8);
        a0[4 + kt] = *(const short8*)(H + (size_t)row0 * HID + kt * 32 + lk * 8);
        a1[4 + kt] = *(const short8*)(H + (size_t)row1 * HID + kt * 32 + lk * 8);
    }

#pragma unroll
    for (int nt2 = 0; nt2 < 2; ++nt2) {
        const int nt = colg * 2 + nt2;
        f32x4 acc0 = {0.f, 0.f, 0.f, 0.f};
        f32x4 acc1 = {0.f, 0.f, 0.f, 0.f};
#pragma unroll
        for (int kt = 0; kt < 8; ++kt) {
            short8 bb = *(const short8*)(Wut + (nt * 16 + lrow) * 256 + kt * 32 + lk * 8);
            acc0 = __builtin_amdgcn_mfma_f32_16x16x32_bf16(a0[kt], bb, acc0, 0, 0, 0);
            acc1 = __builtin_amdgcn_mfma_f32_16x16x32_bf16(a1[kt], bb, acc1, 0, 0, 0);
        }
        const int ocol = nt * 16 + lrow;
        const float bv = bu[ocol];
#pragma unroll
        for (int j = 0; j < 4; ++j) {
            const size_t r0 = (size_t)m0 + lk * 4 + j;
            const size_t r1 = r0 + 16;
            float v0 = acc0[j] + bv; v0 = v0 > 0.f ? v0 : 0.f;
            float v1 = acc1[j] + bv; v1 = v1 > 0.f ? v1 : 0.f;
            Yf[r0 * HID + ocol] = v0;
            Yf[r1 * HID + ocol] = v1;
            if (writeb) {
                Yb[r0 * HID + ocol] = f2b(v0);
                Yb[r1 * HID + ocol] = f2b(v1);
            }
        }
    }
}

extern "C" void kernel_launch(void* const* d_in, const int* in_sizes, int n_in,
                              void* d_out, int out_size, void* d_ws, size_t ws_size,
                              hipStream_t stream) {
    const float* state    = (const float*)d_in[0];
    const float* internal = (const float*)d_in[1];
    const int*   sidx     = (const int*)d_in[2];
    const int*   iidx     = (const int*)d_in[3];
    const float* W1  = (const float*)d_in[4];
    const float* b1  = (const float*)d_in[5];
    const float* W2  = (const float*)d_in[6];
    const float* b2  = (const float*)d_in[7];
    const float* Wu1 = (const float*)d_in[8];
    const float* bu1 = (const float*)d_in[9];
    const float* Wu2 = (const float*)d_in[10];
    const float* bu2 = (const float*)d_in[11];

    float* hu1 = (float*)d_out;
    float* hu2 = hu1 + (size_t)ROWS * HID;

    unsigned short* W1t  = (unsigned short*)d_ws;          // [128][64]
    unsigned short* W2t  = W1t  + 64 * 128;                // [128][128]
    unsigned short* Wu1t = W2t  + 128 * 128;               // [128][256]
    unsigned short* Wu2t = Wu1t + 256 * 128;               // [128][256]
    unsigned short* bufA = Wu2t + 256 * 128;               // [ROWS][128] bf16 each
    unsigned short* bufB = bufA + (size_t)ROWS * HID;
    unsigned short* bufC = bufB + (size_t)ROWS * HID;
    unsigned short* bufD = bufC + (size_t)ROWS * HID;

    const size_t need4 = (size_t)90112 * 2 + 4 * (size_t)ROWS * HID * 2;
    const bool big = ws_size >= need4;

    dim3 b256(256), b512(512);
    const int AGRID = 8 * 2 * NCHUNK;   // 2512

    wconv_all<<<352, b256, 0, stream>>>(W1, W2, Wu1, Wu2, W1t, W2t, Wu1t, Wu2t);

    // layer-1 embeddings: SE1 -> bufA, IE1 -> bufB
    embed_mfma<64, true><<<2500, b256, 0, stream>>>(state, internal, W1t, b1, bufA, bufB);

    if (big) {
        // aggr1 -> bufD; hu1 = relu([aggr1|IE1]@Wu1+bu1) -> d_out + bufC
        aggr_kernel<<<AGRID, b512, 0, stream>>>(bufA, bufB, sidx, iidx, bufD);
        update_gemm<<<1250, b512, 0, stream>>>(bufD, bufB, Wu1t, bu1, hu1, bufC, 1);
        // se2: bufA -> bufB; ie2: bufC -> bufD (one launch, disjoint)
        embed_mfma<128, false><<<2500, b256, 0, stream>>>(bufA, bufC, W2t, b2, bufB, bufD);
        // aggr2 -> bufA; hu2 = relu([aggr2|ie2]@Wu2+bu2) -> d_out
        aggr_kernel<<<AGRID, b512, 0, stream>>>(bufB, bufD, sidx, iidx, bufA);
        update_gemm<<<1250, b512, 0, stream>>>(bufA, bufD, Wu2t, bu2, hu2, nullptr, 0);
    } else {
        // 3-buffer fallback: use the hu2 region (written last) as bf16 scratch.
        unsigned short* Ghu2 = (unsigned short*)hu2;
        aggr_kernel<<<AGRID, b512, 0, stream>>>(bufA, bufB, sidx, iidx, Ghu2);
        update_gemm<<<1250, b512, 0, stream>>>(Ghu2, bufB, Wu1t, bu1, hu1, bufC, 1);
        embed_mfma<128, false><<<1250, b256, 0, stream>>>(bufA, nullptr, W2t, b2, bufB, nullptr);
        embed_mfma<128, false><<<1250, b256, 0, stream>>>(bufC, nullptr, W2t, b2, bufA, nullptr);
        aggr_kernel<<<AGRID, b512, 0, stream>>>(bufB, bufA, sidx, iidx, bufC);
        update_gemm<<<1250, b512, 0, stream>>>(bufC, bufA, Wu2t, bu2, hu2, nullptr, 0);
    }
}

// Round 6
// 231.854 us; speedup vs baseline: 1.0793x; 1.0793x over previous
//
#include <hip/hip_runtime.h>

#define HID 128
#define NNODE 10000
#define KN 16
#define ROWS 80000    // BATCH * NNODE
#define NCHUNK 157    // ceil(NNODE/64)
#define NTILES 2500   // ROWS / 32

typedef __attribute__((ext_vector_type(8))) short short8;   // 8 bf16 (4 VGPRs)
typedef __attribute__((ext_vector_type(4))) float f32x4;
typedef __attribute__((ext_vector_type(2))) float f32x2;
typedef __attribute__((ext_vector_type(4))) unsigned int u32x4;
typedef __attribute__((ext_vector_type(2))) unsigned int u32x2;

__device__ __forceinline__ unsigned short f2b(float f) {
    unsigned u = __float_as_uint(f);
    u += 0x7FFFu + ((u >> 16) & 1u);       // round-to-nearest-even
    return (unsigned short)(u >> 16);
}

// All four weight transposes+converts in one launch.
__global__ __launch_bounds__(256) void wconv_all(
    const float* __restrict__ W1, const float* __restrict__ W2,
    const float* __restrict__ Wu1, const float* __restrict__ Wu2,
    unsigned short* __restrict__ W1t, unsigned short* __restrict__ W2t,
    unsigned short* __restrict__ Wu1t, unsigned short* __restrict__ Wu2t) {
    int idx = blockIdx.x * 256 + threadIdx.x;   // < 90112
    const float* W; unsigned short* Wt; int K; int off;
    if (idx < 8192)       { W = W1;  Wt = W1t;  K = 64;  off = idx; }
    else if (idx < 24576) { W = W2;  Wt = W2t;  K = 128; off = idx - 8192; }
    else if (idx < 57344) { W = Wu1; Wt = Wu1t; K = 256; off = idx - 24576; }
    else                  { W = Wu2; Wt = Wu2t; K = 256; off = idx - 57344; }
    int n = off & 127, k = off >> 7;
    Wt[n * K + k] = f2b(W[off]);
}

// Embed: Y[r][:] = relu(X[r][:] @ W + b), transposed-operand MFMA.
// 8 waves: rs = w&1 (16-row half of a 32-row tile), ng = w>>1 (32-col group).
// W-frags persistent in VGPRs; grid-stride over tiles; 2-deep x pipeline.
// Virtual tile T: T < NTILES -> (A0,Y0), else (A1,Y1).
template<int K, bool AF32>
__global__ __launch_bounds__(512) void embed2(
    const void* __restrict__ A0, const void* __restrict__ A1,
    const unsigned short* __restrict__ Wt, const float* __restrict__ bias,
    unsigned short* __restrict__ Y0, unsigned short* __restrict__ Y1, int tot) {
    const int t = threadIdx.x, w = t >> 6, lane = t & 63;
    const int lrow = lane & 15, lk = lane >> 4;
    const int rs = w & 1, ng = w >> 1;
    const int col0 = ng * 32;

    short8 wf[2][K / 32];
    f32x4 bv[2];
#pragma unroll
    for (int p = 0; p < 2; ++p) {
        bv[p] = *(const f32x4*)(bias + col0 + p * 16 + lk * 4);
#pragma unroll
        for (int kt = 0; kt < K / 32; ++kt)
            wf[p][kt] = *(const short8*)(Wt + (col0 + p * 16 + lrow) * K + kt * 32 + lk * 8);
    }

    int T = blockIdx.x;
    if (T >= tot) return;

    auto loadx = [&](int TT, short8* xf) {
        const int half = TT >= NTILES;
        const void* A = half ? A1 : A0;
        const int row = (TT - half * NTILES) * 32 + rs * 16 + lrow;
        if constexpr (AF32) {
            const float* X = (const float*)A + (size_t)row * K;
#pragma unroll
            for (int kt = 0; kt < K / 32; ++kt) {
                f32x4 f0 = *(const f32x4*)(X + kt * 32 + lk * 8);
                f32x4 f1 = *(const f32x4*)(X + kt * 32 + lk * 8 + 4);
                short8 v;
#pragma unroll
                for (int e = 0; e < 4; ++e) { v[e] = (short)f2b(f0[e]); v[4 + e] = (short)f2b(f1[e]); }
                xf[kt] = v;
            }
        } else {
            const unsigned short* X = (const unsigned short*)A + (size_t)row * K;
#pragma unroll
            for (int kt = 0; kt < K / 32; ++kt)
                xf[kt] = *(const short8*)(X + kt * 32 + lk * 8);
        }
    };

    short8 xf[K / 32], xn[K / 32];
    loadx(T, xf);
    for (;;) {
        const int Tn = T + gridDim.x;
        const bool more = Tn < tot;
        if (more) loadx(Tn, xn);

        const int half = T >= NTILES;
        unsigned short* Y = half ? Y1 : Y0;
        const int row = (T - half * NTILES) * 32 + rs * 16 + lrow;
#pragma unroll
        for (int p = 0; p < 2; ++p) {
            f32x4 acc = {0.f, 0.f, 0.f, 0.f};
#pragma unroll
            for (int kt = 0; kt < K / 32; ++kt)
                acc = __builtin_amdgcn_mfma_f32_16x16x32_bf16(wf[p][kt], xf[kt], acc, 0, 0, 0);
            float v0 = acc[0] + bv[p][0]; v0 = v0 > 0.f ? v0 : 0.f;
            float v1 = acc[1] + bv[p][1]; v1 = v1 > 0.f ? v1 : 0.f;
            float v2 = acc[2] + bv[p][2]; v2 = v2 > 0.f ? v2 : 0.f;
            float v3 = acc[3] + bv[p][3]; v3 = v3 > 0.f ? v3 : 0.f;
            u32x2 ov = {(unsigned)f2b(v0) | ((unsigned)f2b(v1) << 16),
                        (unsigned)f2b(v2) | ((unsigned)f2b(v3) << 16)};
            *(u32x2*)(Y + (size_t)row * HID + col0 + p * 16 + lk * 4) = ov;
        }
        if (!more) break;
#pragma unroll
        for (int kt = 0; kt < K / 32; ++kt) xf[kt] = xn[kt];
        T = Tn;
    }
}

// Stage A: gather + aggregate, column-split so each XCD's working set is
// 2 x 1.28 MB (L2-resident). grid bid = ((h*NCHUNK + c) << 3) | b.
__global__ __launch_bounds__(512) void aggr_kernel(
    const unsigned short* __restrict__ SE, const unsigned short* __restrict__ IE,
    const int* __restrict__ sidx, const int* __restrict__ iidx,
    unsigned short* __restrict__ G) {
    __shared__ int sh_idx[64][33];        // padded: conflict-free write & read
    const int t = threadIdx.x;
    const int b = blockIdx.x & 7;
    const int hc = blockIdx.x >> 3;
    const int h = hc >= NCHUNK ? 1 : 0;
    const int c = hc - h * NCHUNK;
    const int n0 = c * 64;

#pragma unroll
    for (int q = 0; q < 4; ++q) {
        const int e = t + q * 512;        // < 2048
        const int r = e >> 5, k = e & 31;
        int nr = n0 + r; if (nr > NNODE - 1) nr = NNODE - 1;
        sh_idx[r][k] = (k < KN) ? sidx[nr * KN + k] : iidx[nr * KN + (k - KN)];
    }
    __syncthreads();

    const int r = t >> 3, p = t & 7;
    const int col0 = h * 64 + p * 8;
    const int n = n0 + r;
    const size_t base = (size_t)b * NNODE * HID + col0;

    f32x2 acc[4];
#pragma unroll
    for (int w = 0; w < 4; ++w) acc[w] = (f32x2){0.f, 0.f};

#pragma unroll
    for (int q = 0; q < 4; ++q) {
        const unsigned short* P = (q < 2) ? SE : IE;   // slots 0-15 sidx, 16-31 iidx
        u32x4 vals[8];
#pragma unroll
        for (int j = 0; j < 8; ++j)
            vals[j] = *(const u32x4*)(P + base + (size_t)sh_idx[r][q * 8 + j] * HID);
#pragma unroll
        for (int j = 0; j < 8; ++j)
#pragma unroll
            for (int w = 0; w < 4; ++w) {
                const unsigned u = vals[j][w];
                acc[w] += (f32x2){__uint_as_float(u << 16), __uint_as_float(u & 0xffff0000u)};
            }
    }

    if (n < NNODE) {
        short8 ov;
#pragma unroll
        for (int w = 0; w < 4; ++w) {
            ov[2 * w]     = (short)f2b(acc[w].x);
            ov[2 * w + 1] = (short)f2b(acc[w].y);
        }
        *(short8*)(G + ((size_t)b * NNODE + n) * HID + col0) = ov;
    }
}

// Stage B: Y = relu([G|H] @ Wut^T + bu), transposed-operand, persistent W.
// 8 waves: rs = w&1 (rows), ng = w>>1 (32 cols). Grid-stride over 32-row tiles.
__global__ __launch_bounds__(512) void update_gemm2(
    const unsigned short* __restrict__ G, const unsigned short* __restrict__ H,
    const unsigned short* __restrict__ Wut, const float* __restrict__ bu,
    float* __restrict__ Yf, unsigned short* __restrict__ Yb, int writeb) {
    const int t = threadIdx.x, w = t >> 6, lane = t & 63;
    const int lrow = lane & 15, lk = lane >> 4;
    const int rs = w & 1, ng = w >> 1;
    const int col0 = ng * 32;

    short8 wf[2][8];
    f32x4 bv[2];
#pragma unroll
    for (int p = 0; p < 2; ++p) {
        bv[p] = *(const f32x4*)(bu + col0 + p * 16 + lk * 4);
#pragma unroll
        for (int kt = 0; kt < 8; ++kt)
            wf[p][kt] = *(const short8*)(Wut + (col0 + p * 16 + lrow) * 256 + kt * 32 + lk * 8);
    }

    for (int T = blockIdx.x; T < NTILES; T += gridDim.x) {
        const int row = T * 32 + rs * 16 + lrow;
        short8 xf[8];
#pragma unroll
        for (int kt = 0; kt < 4; ++kt) {
            xf[kt]     = *(const short8*)(G + (size_t)row * HID + kt * 32 + lk * 8);
            xf[4 + kt] = *(const short8*)(H + (size_t)row * HID + kt * 32 + lk * 8);
        }
#pragma unroll
        for (int p = 0; p < 2; ++p) {
            f32x4 acc = {0.f, 0.f, 0.f, 0.f};
#pragma unroll
            for (int kt = 0; kt < 8; ++kt)
                acc = __builtin_amdgcn_mfma_f32_16x16x32_bf16(wf[p][kt], xf[kt], acc, 0, 0, 0);
            f32x4 o;
#pragma unroll
            for (int j = 0; j < 4; ++j) {
                float v = acc[j] + bv[p][j];
                o[j] = v > 0.f ? v : 0.f;
            }
            *(f32x4*)(Yf + (size_t)row * HID + col0 + p * 16 + lk * 4) = o;
            if (writeb) {
                u32x2 ov = {(unsigned)f2b(o[0]) | ((unsigned)f2b(o[1]) << 16),
                            (unsigned)f2b(o[2]) | ((unsigned)f2b(o[3]) << 16)};
                *(u32x2*)(Yb + (size_t)row * HID + col0 + p * 16 + lk * 4) = ov;
            }
        }
    }
}

extern "C" void kernel_launch(void* const* d_in, const int* in_sizes, int n_in,
                              void* d_out, int out_size, void* d_ws, size_t ws_size,
                              hipStream_t stream) {
    const float* state    = (const float*)d_in[0];
    const float* internal = (const float*)d_in[1];
    const int*   sidx     = (const int*)d_in[2];
    const int*   iidx     = (const int*)d_in[3];
    const float* W1  = (const float*)d_in[4];
    const float* b1  = (const float*)d_in[5];
    const float* W2  = (const float*)d_in[6];
    const float* b2  = (const float*)d_in[7];
    const float* Wu1 = (const float*)d_in[8];
    const float* bu1 = (const float*)d_in[9];
    const float* Wu2 = (const float*)d_in[10];
    const float* bu2 = (const float*)d_in[11];

    float* hu1 = (float*)d_out;
    float* hu2 = hu1 + (size_t)ROWS * HID;

    unsigned short* W1t  = (unsigned short*)d_ws;          // [128][64]
    unsigned short* W2t  = W1t  + 64 * 128;                // [128][128]
    unsigned short* Wu1t = W2t  + 128 * 128;               // [128][256]
    unsigned short* Wu2t = Wu1t + 256 * 128;               // [128][256]
    unsigned short* bufA = Wu2t + 256 * 128;               // [ROWS][128] bf16 each
    unsigned short* bufB = bufA + (size_t)ROWS * HID;
    unsigned short* bufC = bufB + (size_t)ROWS * HID;
    unsigned short* bufD = bufC + (size_t)ROWS * HID;

    const size_t need4 = (size_t)90112 * 2 + 4 * (size_t)ROWS * HID * 2;
    const bool big = ws_size >= need4;

    dim3 b256(256), b512(512);
    const int AGRID = 8 * 2 * NCHUNK;   // 2512

    wconv_all<<<352, b256, 0, stream>>>(W1, W2, Wu1, Wu2, W1t, W2t, Wu1t, Wu2t);

    // layer-1 embeddings: SE1 -> bufA, IE1 -> bufB (one launch, 5000 tiles)
    embed2<64, true><<<1250, b512, 0, stream>>>(state, internal, W1t, b1, bufA, bufB, 2 * NTILES);

    if (big) {
        // aggr1 -> bufD; hu1 = relu([aggr1|IE1]@Wu1+bu1) -> d_out + bufC
        aggr_kernel<<<AGRID, b512, 0, stream>>>(bufA, bufB, sidx, iidx, bufD);
        update_gemm2<<<1250, b512, 0, stream>>>(bufD, bufB, Wu1t, bu1, hu1, bufC, 1);
        // se2: bufA -> bufB; ie2: bufC -> bufD (one launch, disjoint)
        embed2<128, false><<<1250, b512, 0, stream>>>(bufA, bufC, W2t, b2, bufB, bufD, 2 * NTILES);
        // aggr2 -> bufA; hu2 = relu([aggr2|ie2]@Wu2+bu2) -> d_out
        aggr_kernel<<<AGRID, b512, 0, stream>>>(bufB, bufD, sidx, iidx, bufA);
        update_gemm2<<<1250, b512, 0, stream>>>(bufA, bufD, Wu2t, bu2, hu2, nullptr, 0);
    } else {
        // 3-buffer fallback: use the hu2 region (written last) as bf16 scratch.
        unsigned short* Ghu2 = (unsigned short*)hu2;
        aggr_kernel<<<AGRID, b512, 0, stream>>>(bufA, bufB, sidx, iidx, Ghu2);
        update_gemm2<<<1250, b512, 0, stream>>>(Ghu2, bufB, Wu1t, bu1, hu1, bufC, 1);
        embed2<128, false><<<1250, b512, 0, stream>>>(bufA, nullptr, W2t, b2, bufB, nullptr, NTILES);
        embed2<128, false><<<1250, b512, 0, stream>>>(bufC, nullptr, W2t, b2, bufA, nullptr, NTILES);
        aggr_kernel<<<AGRID, b512, 0, stream>>>(bufB, bufA, sidx, iidx, bufC);
        update_gemm2<<<1250, b512, 0, stream>>>(bufC, bufA, Wu2t, bu2, hu2, nullptr, 0);
    }
}